// Round 17
// baseline (46.477 us; speedup 1.0000x reference)
//
#include <hip/hip_runtime.h>
#include <math.h>

#define NROWS 1546
#define INDIM 1546
#define ODIM  64
#define NDRUG 1373
#define MINN  1e-15f
#define MAXNRM 0.996f   // (1 - 4e-3)/sqrt(c), c=1

#define KSTEPS 49                    // ceil(1546/32); step 48 is the masked tail
#define FRAGSZ (KSTEPS * 4 * 512)    // bf16 elems per packed B matrix = 100352
#define REDS   65                    // padded LDS reduce stride

typedef short  short8 __attribute__((ext_vector_type(8)));
typedef float  f32x4  __attribute__((ext_vector_type(4)));

__device__ __forceinline__ unsigned short f2bf(float f) {   // RNE f32->bf16
    unsigned u = __float_as_uint(f);
    u += 0x7FFFu + ((u >> 16) & 1u);
    return (unsigned short)(u >> 16);
}

__device__ __forceinline__ int fragaddr(int k, int col) {   // B-frag element addr
    return ((k >> 5) * 4 + (col >> 4)) * 512 + (((k & 31) >> 3) * 16 + (col & 15)) * 8 + (k & 7);
}

__device__ __forceinline__ float artanh_(float x) {
    x = fminf(fmaxf(x, -1.0f + 1e-7f), 1.0f - 1e-7f);
    return 0.5f * (log1pf(x) - log1pf(-x));
}

__device__ __forceinline__ float wsum(float v) {
#pragma unroll
    for (int off = 32; off > 0; off >>= 1) v += __shfl_xor(v, off, 64);
    return v;
}

// ---- kernel 1: W -> bf16 B-frags (blocks 0-63), bias (block 64). No adj here. ----
__global__ void prep_kernel(const float* __restrict__ Wd, const float* __restrict__ Wm,
                            unsigned short* __restrict__ WfD, unsigned short* __restrict__ WfM,
                            const float* __restrict__ bd, const float* __restrict__ bm,
                            float* __restrict__ hbD, float* __restrict__ hbM,
                            float* __restrict__ hb2) {
    int tid = threadIdx.x;
    if (blockIdx.x < 64) {
        int total = 64 * 1568;     // 100352 per matrix
        for (int i = blockIdx.x * 256 + tid; i < total; i += 64 * 256) {
            int o = i / 1568, k = i - o * 1568;
            int addr = fragaddr(k, o);
            float vd = (k < INDIM) ? Wd[o * INDIM + k] : 0.f;
            float vm = (k < INDIM) ? Wm[o * INDIM + k] : 0.f;
            WfD[addr] = f2bf(vd);
            WfM[addr] = f2bf(vm);
        }
        return;
    }
    if (tid < 128) {
        int wave = tid >> 6, lane = tid & 63;
        const float* b = wave ? bm : bd;
        float v = b[lane];
        float un2 = wsum(v * v);
        float un = fmaxf(sqrtf(un2), MINN);
        float e = tanhf(un) * v / un;
        float en2 = wsum(e * e);
        float en = fmaxf(sqrtf(en2), MINN);
        float scl = (en > MAXNRM) ? (MAXNRM / en) : 1.0f;
        float* hb = wave ? hbM : hbD;
        hb[lane] = e * scl;
        if (lane == 0) hb2[wave] = en2 * scl * scl;
    }
}

// ---- kernel 2: x@W^T MFMA + in-block reduce + hyperbolic epilogue ----
__global__ __launch_bounds__(512) void liner_fused(
    const float* __restrict__ X,
    const unsigned short* __restrict__ WfD, const unsigned short* __restrict__ WfM,
    const float* __restrict__ hbD, const float* __restrict__ hbM, const float* __restrict__ hb2v,
    float* __restrict__ liner, unsigned short* __restrict__ xtf) {
    __shared__ float red[8][16][REDS];     // 33.3 KB
    int tid = threadIdx.x, kc = tid >> 6, lane = tid & 63;
    int lrow = lane & 15, lgrp = lane >> 4;
    int s = blockIdx.x;                    // 0..97; 97 = strip 85 redo with Wm
    int strip = (s == 97) ? 85 : s;
    int rowbase = strip * 16;
    const unsigned short* Bf = (s <= 85) ? WfD : WfM;
    int lo = (s == 97) ? NDRUG : 0;
    int hi = (s == 85) ? NDRUG : NROWS;

    // phase 0: coalesced full-row norms for this wave's 2 epilogue rows (warms L2)
    float xn2r[2];
#pragma unroll
    for (int j = 0; j < 2; ++j) {
        int gr = min(rowbase + 2 * kc + j, NROWS - 1);
        const float2* src = (const float2*)(X + (size_t)gr * INDIM);
        float ss = 0.f;
        for (int c = lane; c < 773; c += 64) {
            float2 v = src[c];
            ss = fmaf(v.x, v.x, fmaf(v.y, v.y, ss));
        }
        xn2r[j] = wsum(ss);
    }

    const float* arow = X + (size_t)min(rowbase + lrow, NROWS - 1) * INDIM;
    f32x4 ac0 = {0,0,0,0}, ac1 = {0,0,0,0}, ac2 = {0,0,0,0}, ac3 = {0,0,0,0};
#pragma unroll
    for (int ii = 0; ii < 6; ++ii) {       // ksteps kc, kc+8, ..., kc+40
        int ks = kc + 8 * ii;
        const float* xp = arow + ks * 32 + lgrp * 8;
        float2 p0 = *(const float2*)(xp);
        float2 p1 = *(const float2*)(xp + 2);
        float2 p2 = *(const float2*)(xp + 4);
        float2 p3 = *(const float2*)(xp + 6);
        float xv[8] = {p0.x, p0.y, p1.x, p1.y, p2.x, p2.y, p3.x, p3.y};
        short8 av;
#pragma unroll
        for (int j = 0; j < 8; ++j) av[j] = (short)f2bf(xv[j]);
        const unsigned short* bp = Bf + (size_t)(ks * 4) * 512 + lane * 8;
        short8 b0 = *(const short8*)(bp);
        short8 b1 = *(const short8*)(bp + 512);
        short8 b2 = *(const short8*)(bp + 1024);
        short8 b3 = *(const short8*)(bp + 1536);
        ac0 = __builtin_amdgcn_mfma_f32_16x16x32_bf16(av, b0, ac0, 0, 0, 0);
        ac1 = __builtin_amdgcn_mfma_f32_16x16x32_bf16(av, b1, ac1, 0, 0, 0);
        ac2 = __builtin_amdgcn_mfma_f32_16x16x32_bf16(av, b2, ac2, 0, 0, 0);
        ac3 = __builtin_amdgcn_mfma_f32_16x16x32_bf16(av, b3, ac3, 0, 0, 0);
    }
    if (kc == 0) {                         // masked tail kstep 48 (k = 1536..1567)
        short8 av;
#pragma unroll
        for (int j = 0; j < 8; ++j) {
            int k = 1536 + lgrp * 8 + j;
            av[j] = (short)f2bf((k < INDIM) ? arow[k] : 0.f);
        }
        const unsigned short* bp = Bf + (size_t)(48 * 4) * 512 + lane * 8;
        short8 b0 = *(const short8*)(bp);
        short8 b1 = *(const short8*)(bp + 512);
        short8 b2 = *(const short8*)(bp + 1024);
        short8 b3 = *(const short8*)(bp + 1536);
        ac0 = __builtin_amdgcn_mfma_f32_16x16x32_bf16(av, b0, ac0, 0, 0, 0);
        ac1 = __builtin_amdgcn_mfma_f32_16x16x32_bf16(av, b1, ac1, 0, 0, 0);
        ac2 = __builtin_amdgcn_mfma_f32_16x16x32_bf16(av, b2, ac2, 0, 0, 0);
        ac3 = __builtin_amdgcn_mfma_f32_16x16x32_bf16(av, b3, ac3, 0, 0, 0);
    }
    // partials -> LDS (C/D layout: row=lgrp*4+i, col=t*16+lrow)
#pragma unroll
    for (int i = 0; i < 4; ++i) {
        int r = lgrp * 4 + i;
        red[kc][r][lrow]      = ac0[i];
        red[kc][r][16 + lrow] = ac1[i];
        red[kc][r][32 + lrow] = ac2[i];
        red[kc][r][48 + lrow] = ac3[i];
    }
    __syncthreads();

    // epilogue: wave kc handles rows 2kc, 2kc+1 (same wave that owns xn2r)
#pragma unroll
    for (int j = 0; j < 2; ++j) {
        int r = 2 * kc + j;
        int grow = rowbase + r;
        if (grow >= lo && grow < hi) {     // wave-uniform guard
            float mx = 0.f;
#pragma unroll
            for (int w = 0; w < 8; ++w) mx += red[w][r][lane];
            float xn2 = xn2r[j];
            float mxn2 = wsum(mx * mx);
            float xn = fmaxf(sqrtf(xn2), MINN);
            float mxn = fmaxf(sqrtf(mxn2), MINN);
            float g = mxn / xn * artanh_(xn);
            float t = tanhf(g);
            float res = t * mx / mxn;      // |res| == |t|
            float rn = fabsf(t);
            if (rn > MAXNRM) { res *= MAXNRM / rn; rn = MAXNRM; }
            const float* hb = (grow < NDRUG) ? hbD : hbM;
            float y = hb[lane];
            float y2 = hb2v[(grow < NDRUG) ? 0 : 1];
            float x2 = rn * rn;
            float xy = wsum(res * y);
            float num = (1.0f + 2.0f * xy + y2) * res + (1.0f - x2) * y;
            float den = 1.0f + 2.0f * xy + x2 * y2;
            float v = num / fmaxf(den, MINN);
            float v2 = wsum(v * v);
            float vn = fmaxf(sqrtf(v2), MINN);
            if (vn > MAXNRM) { v *= MAXNRM / vn; vn = MAXNRM; }
            float xt = artanh_(vn) / vn * v;   // logmap0
            liner[(size_t)grow * ODIM + lane] = v;
            xtf[fragaddr(grow, lane)] = f2bf(xt);
        }
    }
    if (s == 96) {                         // zero-pad xtf rows 1546..1567
        for (int row = NROWS + kc; row < 1568; row += 8)
            xtf[fragaddr(row, lane)] = 0;
    }
}

// ---- kernel 3: adj copy (coalesced) + adj@xtan MFMA + gated HypAct -> h ----
__global__ __launch_bounds__(512) void agg_fused(
    const float* __restrict__ ADJ, const unsigned short* __restrict__ xtf,
    const float* __restrict__ liner, const float* __restrict__ WN /*[128][64]*/,
    const float* __restrict__ biasnode, float* __restrict__ out_h,
    float* __restrict__ adj_out) {
    __shared__ float red[8][16][REDS];     // 33.3 KB
    __shared__ float zl[16][128];          // 8 KB
    int tid = threadIdx.x, kc = tid >> 6, lane = tid & 63;
    int lrow = lane & 15, lgrp = lane >> 4;
    int rowbase = blockIdx.x * 16;         // 97 blocks

    // phase 0: coalesced copy of this block's 16 adj rows (also warms L2 for GEMM)
#pragma unroll
    for (int j = 0; j < 2; ++j) {
        int gr = rowbase + 2 * kc + j;
        if (gr < NROWS) {
            const float2* src = (const float2*)(ADJ + (size_t)gr * INDIM);
            float2* dst = (float2*)(adj_out + (size_t)gr * INDIM);
            for (int c = lane; c < 773; c += 64) dst[c] = src[c];
        }
    }

    const float* arow = ADJ + (size_t)min(rowbase + lrow, NROWS - 1) * INDIM;
    f32x4 ac0 = {0,0,0,0}, ac1 = {0,0,0,0}, ac2 = {0,0,0,0}, ac3 = {0,0,0,0};
#pragma unroll
    for (int ii = 0; ii < 6; ++ii) {
        int ks = kc + 8 * ii;
        const float* xp = arow + ks * 32 + lgrp * 8;
        float2 p0 = *(const float2*)(xp);
        float2 p1 = *(const float2*)(xp + 2);
        float2 p2 = *(const float2*)(xp + 4);
        float2 p3 = *(const float2*)(xp + 6);
        float xv[8] = {p0.x, p0.y, p1.x, p1.y, p2.x, p2.y, p3.x, p3.y};
        short8 av;
#pragma unroll
        for (int j = 0; j < 8; ++j) av[j] = (short)f2bf(xv[j]);
        const unsigned short* bp = xtf + (size_t)(ks * 4) * 512 + lane * 8;
        short8 b0 = *(const short8*)(bp);
        short8 b1 = *(const short8*)(bp + 512);
        short8 b2 = *(const short8*)(bp + 1024);
        short8 b3 = *(const short8*)(bp + 1536);
        ac0 = __builtin_amdgcn_mfma_f32_16x16x32_bf16(av, b0, ac0, 0, 0, 0);
        ac1 = __builtin_amdgcn_mfma_f32_16x16x32_bf16(av, b1, ac1, 0, 0, 0);
        ac2 = __builtin_amdgcn_mfma_f32_16x16x32_bf16(av, b2, ac2, 0, 0, 0);
        ac3 = __builtin_amdgcn_mfma_f32_16x16x32_bf16(av, b3, ac3, 0, 0, 0);
    }
    if (kc == 0) {                         // masked tail kstep 48
        short8 av;
#pragma unroll
        for (int j = 0; j < 8; ++j) {
            int k = 1536 + lgrp * 8 + j;
            av[j] = (short)f2bf((k < INDIM) ? arow[k] : 0.f);
        }
        const unsigned short* bp = xtf + (size_t)(48 * 4) * 512 + lane * 8;
        short8 b0 = *(const short8*)(bp);
        short8 b1 = *(const short8*)(bp + 512);
        short8 b2 = *(const short8*)(bp + 1024);
        short8 b3 = *(const short8*)(bp + 1536);
        ac0 = __builtin_amdgcn_mfma_f32_16x16x32_bf16(av, b0, ac0, 0, 0, 0);
        ac1 = __builtin_amdgcn_mfma_f32_16x16x32_bf16(av, b1, ac1, 0, 0, 0);
        ac2 = __builtin_amdgcn_mfma_f32_16x16x32_bf16(av, b2, ac2, 0, 0, 0);
        ac3 = __builtin_amdgcn_mfma_f32_16x16x32_bf16(av, b3, ac3, 0, 0, 0);
    }
#pragma unroll
    for (int i = 0; i < 4; ++i) {
        int r = lgrp * 4 + i;
        red[kc][r][lrow]      = ac0[i];
        red[kc][r][16 + lrow] = ac1[i];
        red[kc][r][32 + lrow] = ac2[i];
        red[kc][r][48 + lrow] = ac3[i];
    }
    __syncthreads();

#pragma unroll
    for (int j = 0; j < 2; ++j) {
        int r = 2 * kc + j;
        int grow = rowbase + r;
        if (grow < NROWS) {
            float sv = 0.f;
#pragma unroll
            for (int w = 0; w < 8; ++w) sv += red[w][r][lane];
            float sn2 = wsum(sv * sv);
            float sn = fmaxf(sqrtf(sn2), MINN);
            float th = tanhf(sn);
            float agg = th * sv / sn;          // expmap0; |agg| == th
            if (th > MAXNRM) agg *= MAXNRM / th;
            float lin = liner[(size_t)grow * ODIM + lane];
            zl[r][lane] = agg;
            zl[r][64 + lane] = lin;            // same-wave LDS RAW, no barrier needed
            float d = biasnode[grow];
            const float* w = WN + lane;
#pragma unroll 8
            for (int f = 0; f < 128; ++f) d = fmaf(zl[r][f], w[f * 64], d);
            d = fmaxf(d, 0.0f);
            out_h[(size_t)grow * ODIM + lane] = d * agg + (1.0f - d) * lin;
        }
    }
}

extern "C" void kernel_launch(void* const* d_in, const int* in_sizes, int n_in,
                              void* d_out, int out_size, void* d_ws, size_t ws_size,
                              hipStream_t stream) {
    const float* x   = (const float*)d_in[0];
    const float* adj = (const float*)d_in[1];
    const float* Wd  = (const float*)d_in[2];
    const float* Wm  = (const float*)d_in[3];
    const float* bd  = (const float*)d_in[4];
    const float* bm  = (const float*)d_in[5];
    const float* wn  = (const float*)d_in[6];
    const float* bn  = (const float*)d_in[7];
    float* out = (float*)d_out;

    const int WELEMS = ODIM * INDIM;              // 98944
    unsigned short* WfD = (unsigned short*)d_ws;  // 100352 ushorts each
    unsigned short* WfM = WfD + FRAGSZ;
    unsigned short* xtf = WfM + FRAGSZ;
    float* hbD   = (float*)(xtf + FRAGSZ);        // 3*200704 B -> 4B-aligned
    float* hbM   = hbD + 64;
    float* hb2   = hbM + 64;
    float* liner = hbD + 192;                     // 98944

    prep_kernel<<<65, 256, 0, stream>>>(Wd, Wm, WfD, WfM, bd, bm, hbD, hbM, hb2);
    liner_fused<<<98, 512, 0, stream>>>(x, WfD, WfM, hbD, hbM, hb2, liner, xtf);
    agg_fused<<<97, 512, 0, stream>>>(adj, xtf, liner, wn, bn, out, out + WELEMS);
}

// Round 18
// 38.038 us; speedup vs baseline: 1.2219x; 1.2219x over previous
//
#include <hip/hip_runtime.h>
#include <math.h>

#define NROWS 1546
#define INDIM 1546
#define ODIM  64
#define NDRUG 1373
#define MINN  1e-15f
#define MAXNRM 0.996f   // (1 - 4e-3)/sqrt(c), c=1

#define KSTEPS 49                    // ceil(1546/32); step 48 is the masked tail
#define FRAGSZ (KSTEPS * 4 * 512)    // bf16 elems per packed B matrix = 100352
#define REDS   65                    // padded LDS reduce stride
#define GEMMB  98                    // GEMM blocks in liner_fused; rest copy adj

typedef short  short8 __attribute__((ext_vector_type(8)));
typedef float  f32x4  __attribute__((ext_vector_type(4)));

__device__ __forceinline__ unsigned short f2bf(float f) {   // RNE f32->bf16
    unsigned u = __float_as_uint(f);
    u += 0x7FFFu + ((u >> 16) & 1u);
    return (unsigned short)(u >> 16);
}

__device__ __forceinline__ int fragaddr(int k, int col) {   // B-frag element addr
    return ((k >> 5) * 4 + (col >> 4)) * 512 + (((k & 31) >> 3) * 16 + (col & 15)) * 8 + (k & 7);
}

__device__ __forceinline__ float artanh_(float x) {
    x = fminf(fmaxf(x, -1.0f + 1e-7f), 1.0f - 1e-7f);
    return 0.5f * (log1pf(x) - log1pf(-x));
}

__device__ __forceinline__ float wsum(float v) {
#pragma unroll
    for (int off = 32; off > 0; off >>= 1) v += __shfl_xor(v, off, 64);
    return v;
}

// ---- kernel 1: W -> bf16 B-frags (blocks 0-63), bias (block 64) ----
__global__ void prep_kernel(const float* __restrict__ Wd, const float* __restrict__ Wm,
                            unsigned short* __restrict__ WfD, unsigned short* __restrict__ WfM,
                            const float* __restrict__ bd, const float* __restrict__ bm,
                            float* __restrict__ hbD, float* __restrict__ hbM,
                            float* __restrict__ hb2) {
    int tid = threadIdx.x;
    if (blockIdx.x < 64) {
        int total = 64 * 1568;     // 100352 per matrix
        for (int i = blockIdx.x * 256 + tid; i < total; i += 64 * 256) {
            int o = i / 1568, k = i - o * 1568;
            int addr = fragaddr(k, o);
            float vd = (k < INDIM) ? Wd[o * INDIM + k] : 0.f;
            float vm = (k < INDIM) ? Wm[o * INDIM + k] : 0.f;
            WfD[addr] = f2bf(vd);
            WfM[addr] = f2bf(vm);
        }
        return;
    }
    if (tid < 128) {
        int wave = tid >> 6, lane = tid & 63;
        const float* b = wave ? bm : bd;
        float v = b[lane];
        float un2 = wsum(v * v);
        float un = fmaxf(sqrtf(un2), MINN);
        float e = tanhf(un) * v / un;
        float en2 = wsum(e * e);
        float en = fmaxf(sqrtf(en2), MINN);
        float scl = (en > MAXNRM) ? (MAXNRM / en) : 1.0f;
        float* hb = wave ? hbM : hbD;
        hb[lane] = e * scl;
        if (lane == 0) hb2[wave] = en2 * scl * scl;
    }
}

// ---- kernel 2: blocks 0-97: x@W^T MFMA + reduce + hyperbolic epilogue;
//                blocks 98+: grid-stride adj copy on otherwise-idle CUs ----
__global__ __launch_bounds__(512) void liner_fused(
    const float* __restrict__ X,
    const unsigned short* __restrict__ WfD, const unsigned short* __restrict__ WfM,
    const float* __restrict__ hbD, const float* __restrict__ hbM, const float* __restrict__ hb2v,
    float* __restrict__ liner, unsigned short* __restrict__ xtf,
    const float4* __restrict__ adj4, float4* __restrict__ adjout4, int n4) {
    __shared__ float red[8][16][REDS];     // 33.3 KB
    __shared__ float ssl[8][16];
    int tid = threadIdx.x, kc = tid >> 6, lane = tid & 63;

    if (blockIdx.x >= GEMMB) {             // copy blocks: overlap adj copy with GEMM
        int nb = gridDim.x - GEMMB;
        for (int i = (blockIdx.x - GEMMB) * 512 + tid; i < n4; i += nb * 512)
            adjout4[i] = adj4[i];
        return;
    }

    int lrow = lane & 15, lgrp = lane >> 4;
    int s = blockIdx.x;                    // 0..97; 97 = strip 85 redo with Wm
    int strip = (s == 97) ? 85 : s;
    int rowbase = strip * 16;
    const unsigned short* Bf = (s <= 85) ? WfD : WfM;
    int lo = (s == 97) ? NDRUG : 0;
    int hi = (s == 85) ? NDRUG : NROWS;
    const float* arow = X + (size_t)min(rowbase + lrow, NROWS - 1) * INDIM;

    f32x4 ac0 = {0,0,0,0}, ac1 = {0,0,0,0}, ac2 = {0,0,0,0}, ac3 = {0,0,0,0};
    float ss = 0.f;
    for (int ks = kc; ks < 48; ks += 8) {  // 6 full k-steps per wave
        const float* xp = arow + ks * 32 + lgrp * 8;
        float2 p0 = *(const float2*)(xp);
        float2 p1 = *(const float2*)(xp + 2);
        float2 p2 = *(const float2*)(xp + 4);
        float2 p3 = *(const float2*)(xp + 6);
        float xv[8] = {p0.x, p0.y, p1.x, p1.y, p2.x, p2.y, p3.x, p3.y};
        short8 av;
#pragma unroll
        for (int j = 0; j < 8; ++j) { ss = fmaf(xv[j], xv[j], ss); av[j] = (short)f2bf(xv[j]); }
        const unsigned short* bp = Bf + (size_t)(ks * 4) * 512 + lane * 8;
        short8 b0 = *(const short8*)(bp);
        short8 b1 = *(const short8*)(bp + 512);
        short8 b2 = *(const short8*)(bp + 1024);
        short8 b3 = *(const short8*)(bp + 1536);
        ac0 = __builtin_amdgcn_mfma_f32_16x16x32_bf16(av, b0, ac0, 0, 0, 0);
        ac1 = __builtin_amdgcn_mfma_f32_16x16x32_bf16(av, b1, ac1, 0, 0, 0);
        ac2 = __builtin_amdgcn_mfma_f32_16x16x32_bf16(av, b2, ac2, 0, 0, 0);
        ac3 = __builtin_amdgcn_mfma_f32_16x16x32_bf16(av, b3, ac3, 0, 0, 0);
    }
    if (kc == 0) {                         // masked tail kstep 48 (k = 1536..1567)
        short8 av;
#pragma unroll
        for (int j = 0; j < 8; ++j) {
            int k = 1536 + lgrp * 8 + j;
            float v = (k < INDIM) ? arow[k] : 0.f;
            ss = fmaf(v, v, ss);
            av[j] = (short)f2bf(v);
        }
        const unsigned short* bp = Bf + (size_t)(48 * 4) * 512 + lane * 8;
        short8 b0 = *(const short8*)(bp);
        short8 b1 = *(const short8*)(bp + 512);
        short8 b2 = *(const short8*)(bp + 1024);
        short8 b3 = *(const short8*)(bp + 1536);
        ac0 = __builtin_amdgcn_mfma_f32_16x16x32_bf16(av, b0, ac0, 0, 0, 0);
        ac1 = __builtin_amdgcn_mfma_f32_16x16x32_bf16(av, b1, ac1, 0, 0, 0);
        ac2 = __builtin_amdgcn_mfma_f32_16x16x32_bf16(av, b2, ac2, 0, 0, 0);
        ac3 = __builtin_amdgcn_mfma_f32_16x16x32_bf16(av, b3, ac3, 0, 0, 0);
    }
    // per-row Σx² within this wave's k-subset
    ss += __shfl_xor(ss, 16, 64);
    ss += __shfl_xor(ss, 32, 64);
    if (lane < 16) ssl[kc][lrow] = ss;
    // partials -> LDS (C/D layout: row=lgrp*4+i, col=t*16+lrow)
#pragma unroll
    for (int i = 0; i < 4; ++i) {
        int r = lgrp * 4 + i;
        red[kc][r][lrow]      = ac0[i];
        red[kc][r][16 + lrow] = ac1[i];
        red[kc][r][32 + lrow] = ac2[i];
        red[kc][r][48 + lrow] = ac3[i];
    }
    __syncthreads();

    // epilogue: wave kc handles rows 2kc, 2kc+1
#pragma unroll
    for (int j = 0; j < 2; ++j) {
        int r = 2 * kc + j;
        int grow = rowbase + r;
        if (grow >= lo && grow < hi) {     // wave-uniform guard
            float mx = 0.f, xn2 = 0.f;
#pragma unroll
            for (int w = 0; w < 8; ++w) { mx += red[w][r][lane]; xn2 += ssl[w][r]; }
            float mxn2 = wsum(mx * mx);
            float xn = fmaxf(sqrtf(xn2), MINN);
            float mxn = fmaxf(sqrtf(mxn2), MINN);
            float g = mxn / xn * artanh_(xn);
            float t = tanhf(g);
            float res = t * mx / mxn;      // |res| == |t|
            float rn = fabsf(t);
            if (rn > MAXNRM) { res *= MAXNRM / rn; rn = MAXNRM; }
            const float* hb = (grow < NDRUG) ? hbD : hbM;
            float y = hb[lane];
            float y2 = hb2v[(grow < NDRUG) ? 0 : 1];
            float x2 = rn * rn;
            float xy = wsum(res * y);
            float num = (1.0f + 2.0f * xy + y2) * res + (1.0f - x2) * y;
            float den = 1.0f + 2.0f * xy + x2 * y2;
            float v = num / fmaxf(den, MINN);
            float v2 = wsum(v * v);
            float vn = fmaxf(sqrtf(v2), MINN);
            if (vn > MAXNRM) { v *= MAXNRM / vn; vn = MAXNRM; }
            float xt = artanh_(vn) / vn * v;   // logmap0
            liner[(size_t)grow * ODIM + lane] = v;
            xtf[fragaddr(grow, lane)] = f2bf(xt);
        }
    }
    if (s == 96) {                         // zero-pad xtf rows 1546..1567
        for (int row = NROWS + kc; row < 1568; row += 8)
            xtf[fragaddr(row, lane)] = 0;
    }
}

// ---- kernel 3: adj@xtan MFMA + in-block reduce + gated HypAct -> h ----
__global__ __launch_bounds__(512) void agg_fused(
    const float* __restrict__ ADJ, const unsigned short* __restrict__ xtf,
    const float* __restrict__ liner, const float* __restrict__ WN /*[128][64]*/,
    const float* __restrict__ biasnode, float* __restrict__ out_h) {
    __shared__ float red[8][16][REDS];     // 33.3 KB
    __shared__ float zl[16][128];          // 8 KB
    int tid = threadIdx.x, kc = tid >> 6, lane = tid & 63;
    int lrow = lane & 15, lgrp = lane >> 4;
    int rowbase = blockIdx.x * 16;         // 97 blocks
    const float* arow = ADJ + (size_t)min(rowbase + lrow, NROWS - 1) * INDIM;

    f32x4 ac0 = {0,0,0,0}, ac1 = {0,0,0,0}, ac2 = {0,0,0,0}, ac3 = {0,0,0,0};
    for (int ks = kc; ks < 48; ks += 8) {
        const float* xp = arow + ks * 32 + lgrp * 8;
        float2 p0 = *(const float2*)(xp);
        float2 p1 = *(const float2*)(xp + 2);
        float2 p2 = *(const float2*)(xp + 4);
        float2 p3 = *(const float2*)(xp + 6);
        float xv[8] = {p0.x, p0.y, p1.x, p1.y, p2.x, p2.y, p3.x, p3.y};
        short8 av;
#pragma unroll
        for (int j = 0; j < 8; ++j) av[j] = (short)f2bf(xv[j]);
        const unsigned short* bp = xtf + (size_t)(ks * 4) * 512 + lane * 8;
        short8 b0 = *(const short8*)(bp);
        short8 b1 = *(const short8*)(bp + 512);
        short8 b2 = *(const short8*)(bp + 1024);
        short8 b3 = *(const short8*)(bp + 1536);
        ac0 = __builtin_amdgcn_mfma_f32_16x16x32_bf16(av, b0, ac0, 0, 0, 0);
        ac1 = __builtin_amdgcn_mfma_f32_16x16x32_bf16(av, b1, ac1, 0, 0, 0);
        ac2 = __builtin_amdgcn_mfma_f32_16x16x32_bf16(av, b2, ac2, 0, 0, 0);
        ac3 = __builtin_amdgcn_mfma_f32_16x16x32_bf16(av, b3, ac3, 0, 0, 0);
    }
    if (kc == 0) {                         // masked tail kstep 48
        short8 av;
#pragma unroll
        for (int j = 0; j < 8; ++j) {
            int k = 1536 + lgrp * 8 + j;
            av[j] = (short)f2bf((k < INDIM) ? arow[k] : 0.f);
        }
        const unsigned short* bp = xtf + (size_t)(48 * 4) * 512 + lane * 8;
        short8 b0 = *(const short8*)(bp);
        short8 b1 = *(const short8*)(bp + 512);
        short8 b2 = *(const short8*)(bp + 1024);
        short8 b3 = *(const short8*)(bp + 1536);
        ac0 = __builtin_amdgcn_mfma_f32_16x16x32_bf16(av, b0, ac0, 0, 0, 0);
        ac1 = __builtin_amdgcn_mfma_f32_16x16x32_bf16(av, b1, ac1, 0, 0, 0);
        ac2 = __builtin_amdgcn_mfma_f32_16x16x32_bf16(av, b2, ac2, 0, 0, 0);
        ac3 = __builtin_amdgcn_mfma_f32_16x16x32_bf16(av, b3, ac3, 0, 0, 0);
    }
#pragma unroll
    for (int i = 0; i < 4; ++i) {
        int r = lgrp * 4 + i;
        red[kc][r][lrow]      = ac0[i];
        red[kc][r][16 + lrow] = ac1[i];
        red[kc][r][32 + lrow] = ac2[i];
        red[kc][r][48 + lrow] = ac3[i];
    }
    __syncthreads();

#pragma unroll
    for (int j = 0; j < 2; ++j) {
        int r = 2 * kc + j;
        int grow = rowbase + r;
        if (grow < NROWS) {
            float sv = 0.f;
#pragma unroll
            for (int w = 0; w < 8; ++w) sv += red[w][r][lane];
            float sn2 = wsum(sv * sv);
            float sn = fmaxf(sqrtf(sn2), MINN);
            float th = tanhf(sn);
            float agg = th * sv / sn;          // expmap0; |agg| == th
            if (th > MAXNRM) agg *= MAXNRM / th;
            float lin = liner[(size_t)grow * ODIM + lane];
            zl[r][lane] = agg;
            zl[r][64 + lane] = lin;            // same-wave LDS RAW, no barrier needed
            float d = biasnode[grow];
            const float* w = WN + lane;
#pragma unroll 8
            for (int f = 0; f < 128; ++f) d = fmaf(zl[r][f], w[f * 64], d);
            d = fmaxf(d, 0.0f);
            out_h[(size_t)grow * ODIM + lane] = d * agg + (1.0f - d) * lin;
        }
    }
}

extern "C" void kernel_launch(void* const* d_in, const int* in_sizes, int n_in,
                              void* d_out, int out_size, void* d_ws, size_t ws_size,
                              hipStream_t stream) {
    const float* x   = (const float*)d_in[0];
    const float* adj = (const float*)d_in[1];
    const float* Wd  = (const float*)d_in[2];
    const float* Wm  = (const float*)d_in[3];
    const float* bd  = (const float*)d_in[4];
    const float* bm  = (const float*)d_in[5];
    const float* wn  = (const float*)d_in[6];
    const float* bn  = (const float*)d_in[7];
    float* out = (float*)d_out;

    const int WELEMS = ODIM * INDIM;              // 98944
    unsigned short* WfD = (unsigned short*)d_ws;  // 100352 ushorts each
    unsigned short* WfM = WfD + FRAGSZ;
    unsigned short* xtf = WfM + FRAGSZ;
    float* hbD   = (float*)(xtf + FRAGSZ);        // 3*200704 B -> 4B-aligned
    float* hbM   = hbD + 64;
    float* hb2   = hbM + 64;
    float* liner = hbD + 192;                     // 98944

    int n4 = (NROWS * NROWS) / 4;                 // 597529
    prep_kernel<<<65, 256, 0, stream>>>(Wd, Wm, WfD, WfM, bd, bm, hbD, hbM, hb2);
    liner_fused<<<258, 512, 0, stream>>>(x, WfD, WfM, hbD, hbM, hb2, liner, xtf,
                                         (const float4*)adj, (float4*)(out + WELEMS), n4);
    agg_fused<<<97, 512, 0, stream>>>(adj, xtf, liner, wn, bn, out);
}

// Round 19
// 33.060 us; speedup vs baseline: 1.4059x; 1.1506x over previous
//
#include <hip/hip_runtime.h>
#include <math.h>

#define NROWS 1546
#define INDIM 1546
#define ODIM  64
#define NDRUG 1373
#define MINN  1e-15f
#define MAXNRM 0.996f   // (1 - 4e-3)/sqrt(c), c=1

#define KSTEPS 49                    // ceil(1546/32); step 48 is the masked tail
#define FRAGSZ (KSTEPS * 4 * 512)    // bf16 elems per packed B matrix = 100352
#define REDS   65                    // padded LDS reduce stride

typedef short  short8 __attribute__((ext_vector_type(8)));
typedef float  f32x4  __attribute__((ext_vector_type(4)));

__device__ __forceinline__ unsigned short f2bf(float f) {   // RNE f32->bf16
    unsigned u = __float_as_uint(f);
    u += 0x7FFFu + ((u >> 16) & 1u);
    return (unsigned short)(u >> 16);
}

__device__ __forceinline__ int fragaddr(int k, int col) {   // B-frag element addr
    return ((k >> 5) * 4 + (col >> 4)) * 512 + (((k & 31) >> 3) * 16 + (col & 15)) * 8 + (k & 7);
}

__device__ __forceinline__ float artanh_(float x) {
    x = fminf(fmaxf(x, -1.0f + 1e-7f), 1.0f - 1e-7f);
    return 0.5f * (log1pf(x) - log1pf(-x));
}

__device__ __forceinline__ float wsum(float v) {
#pragma unroll
    for (int off = 32; off > 0; off >>= 1) v += __shfl_xor(v, off, 64);
    return v;
}

// ---- kernel 1: W -> bf16 B-frags (blocks 0-63), bias (64), adj copy (65+) ----
__global__ void prep_kernel(const float* __restrict__ Wd, const float* __restrict__ Wm,
                            unsigned short* __restrict__ WfD, unsigned short* __restrict__ WfM,
                            const float* __restrict__ bd, const float* __restrict__ bm,
                            float* __restrict__ hbD, float* __restrict__ hbM,
                            float* __restrict__ hb2,
                            const float4* __restrict__ adj4, float4* __restrict__ adjout4,
                            int n4) {
    int tid = threadIdx.x;
    if (blockIdx.x < 64) {
        int total = 64 * 1568;     // 100352 per matrix
        for (int i = blockIdx.x * 256 + tid; i < total; i += 64 * 256) {
            int o = i / 1568, k = i - o * 1568;
            int addr = fragaddr(k, o);
            float vd = (k < INDIM) ? Wd[o * INDIM + k] : 0.f;
            float vm = (k < INDIM) ? Wm[o * INDIM + k] : 0.f;
            WfD[addr] = f2bf(vd);
            WfM[addr] = f2bf(vm);
        }
        return;
    }
    if (blockIdx.x == 64) {
        if (tid < 128) {
            int wave = tid >> 6, lane = tid & 63;
            const float* b = wave ? bm : bd;
            float v = b[lane];
            float un2 = wsum(v * v);
            float un = fmaxf(sqrtf(un2), MINN);
            float e = tanhf(un) * v / un;
            float en2 = wsum(e * e);
            float en = fmaxf(sqrtf(en2), MINN);
            float scl = (en > MAXNRM) ? (MAXNRM / en) : 1.0f;
            float* hb = wave ? hbM : hbD;
            hb[lane] = e * scl;
            if (lane == 0) hb2[wave] = en2 * scl * scl;
        }
        return;
    }
    int nb = gridDim.x - 65;
    for (int i = (blockIdx.x - 65) * 256 + tid; i < n4; i += nb * 256)
        adjout4[i] = adj4[i];
}

// ---- kernel 2: x@W^T MFMA, 2 blocks per strip (K halves), in-block 4-wave reduce ----
__global__ __launch_bounds__(256) void gemm_liner_mfma(
    const float* __restrict__ X,
    const unsigned short* __restrict__ WfD, const unsigned short* __restrict__ WfM,
    float* __restrict__ part, float* __restrict__ pnorm) {
    __shared__ float red[4][16][REDS];   // 16.6 KB
    __shared__ float ssl[4][16];
    int tid = threadIdx.x, wave = tid >> 6, lane = tid & 63;
    int lrow = lane & 15, lgrp = lane >> 4;
    int s = blockIdx.x;                  // 0..97; 97 = strip 85 redo with Wm
    int h = blockIdx.y;                  // K half
    int kc = h * 4 + wave;               // 0..7
    int strip = (s == 97) ? 85 : s;
    int rowbase = strip * 16;
    const unsigned short* Bf = (s <= 85) ? WfD : WfM;
    int lo = (s == 97) ? NDRUG : 0;
    int hi = (s == 85) ? NDRUG : NROWS;
    const float* arow = X + (size_t)min(rowbase + lrow, NROWS - 1) * INDIM;

    f32x4 ac0 = {0,0,0,0}, ac1 = {0,0,0,0}, ac2 = {0,0,0,0}, ac3 = {0,0,0,0};
    float ss = 0.f;
    for (int ks = kc; ks < 48; ks += 8) {   // 6 k-steps per wave
        const float* xp = arow + ks * 32 + lgrp * 8;
        float2 p0 = *(const float2*)(xp);
        float2 p1 = *(const float2*)(xp + 2);
        float2 p2 = *(const float2*)(xp + 4);
        float2 p3 = *(const float2*)(xp + 6);
        float xv[8] = {p0.x, p0.y, p1.x, p1.y, p2.x, p2.y, p3.x, p3.y};
        short8 av;
#pragma unroll
        for (int j = 0; j < 8; ++j) { ss = fmaf(xv[j], xv[j], ss); av[j] = (short)f2bf(xv[j]); }
        const unsigned short* bp = Bf + (size_t)(ks * 4) * 512 + lane * 8;
        short8 b0 = *(const short8*)(bp);
        short8 b1 = *(const short8*)(bp + 512);
        short8 b2 = *(const short8*)(bp + 1024);
        short8 b3 = *(const short8*)(bp + 1536);
        ac0 = __builtin_amdgcn_mfma_f32_16x16x32_bf16(av, b0, ac0, 0, 0, 0);
        ac1 = __builtin_amdgcn_mfma_f32_16x16x32_bf16(av, b1, ac1, 0, 0, 0);
        ac2 = __builtin_amdgcn_mfma_f32_16x16x32_bf16(av, b2, ac2, 0, 0, 0);
        ac3 = __builtin_amdgcn_mfma_f32_16x16x32_bf16(av, b3, ac3, 0, 0, 0);
    }
    if (kc == 0) {                       // masked tail kstep 48 (k = 1536..1567)
        short8 av;
#pragma unroll
        for (int j = 0; j < 8; ++j) {
            int k = 1536 + lgrp * 8 + j;
            float v = (k < INDIM) ? arow[k] : 0.f;
            ss = fmaf(v, v, ss);
            av[j] = (short)f2bf(v);
        }
        const unsigned short* bp = Bf + (size_t)(48 * 4) * 512 + lane * 8;
        short8 b0 = *(const short8*)(bp);
        short8 b1 = *(const short8*)(bp + 512);
        short8 b2 = *(const short8*)(bp + 1024);
        short8 b3 = *(const short8*)(bp + 1536);
        ac0 = __builtin_amdgcn_mfma_f32_16x16x32_bf16(av, b0, ac0, 0, 0, 0);
        ac1 = __builtin_amdgcn_mfma_f32_16x16x32_bf16(av, b1, ac1, 0, 0, 0);
        ac2 = __builtin_amdgcn_mfma_f32_16x16x32_bf16(av, b2, ac2, 0, 0, 0);
        ac3 = __builtin_amdgcn_mfma_f32_16x16x32_bf16(av, b3, ac3, 0, 0, 0);
    }
    ss += __shfl_xor(ss, 16, 64);        // sum 4 lane-groups sharing a row
    ss += __shfl_xor(ss, 32, 64);
    if (lane < 16) ssl[wave][lrow] = ss;
#pragma unroll
    for (int i = 0; i < 4; ++i) {        // C/D layout: row=lgrp*4+i, col=t*16+lrow
        int r = lgrp * 4 + i;
        red[wave][r][lrow]      = ac0[i];
        red[wave][r][16 + lrow] = ac1[i];
        red[wave][r][32 + lrow] = ac2[i];
        red[wave][r][48 + lrow] = ac3[i];
    }
    __syncthreads();

#pragma unroll
    for (int j = 0; j < 4; ++j) {        // wave handles 4 rows
        int r = wave * 4 + j;
        int grow = rowbase + r;
        if (grow >= lo && grow < hi) {
            float p = red[0][r][lane] + red[1][r][lane] + red[2][r][lane] + red[3][r][lane];
            part[(size_t)(grow * 2 + h) * 64 + lane] = p;
        }
        if (s != 97 && grow < NROWS && lane == 0) {   // row norms: W-independent
            pnorm[grow * 2 + h] = ssl[0][r] + ssl[1][r] + ssl[2][r] + ssl[3][r];
        }
    }
}

// ---- kernel 3: reduce 2 partials + hyperbolic epilogue -> liner, xtf ----
__global__ __launch_bounds__(512) void linerB(
    const float* __restrict__ part, const float* __restrict__ pnorm,
    const float* __restrict__ hbD, const float* __restrict__ hbM, const float* __restrict__ hb2v,
    float* __restrict__ liner, unsigned short* __restrict__ xtf) {
    int wave = threadIdx.x >> 6, lane = threadIdx.x & 63;
    int grow = blockIdx.x * 8 + wave;
    if (grow >= NROWS) {                 // block 193 waves 2-7: zero-pad rows 1546..1567
        for (int row = grow; row < 1568; row += 6)
            xtf[fragaddr(row, lane)] = 0;
        return;
    }
    float mx = part[(size_t)(grow * 2) * 64 + lane] + part[(size_t)(grow * 2 + 1) * 64 + lane];
    float xn2 = pnorm[grow * 2] + pnorm[grow * 2 + 1];

    float mxn2 = wsum(mx * mx);
    float xn = fmaxf(sqrtf(xn2), MINN);
    float mxn = fmaxf(sqrtf(mxn2), MINN);
    float g = mxn / xn * artanh_(xn);
    float t = tanhf(g);
    float res = t * mx / mxn;            // |res| == |t|
    float rn = fabsf(t);
    if (rn > MAXNRM) { res *= MAXNRM / rn; rn = MAXNRM; }
    const float* hb = (grow < NDRUG) ? hbD : hbM;
    float y = hb[lane];
    float y2 = hb2v[(grow < NDRUG) ? 0 : 1];
    float x2 = rn * rn;
    float xy = wsum(res * y);
    float num = (1.0f + 2.0f * xy + y2) * res + (1.0f - x2) * y;
    float den = 1.0f + 2.0f * xy + x2 * y2;
    float v = num / fmaxf(den, MINN);
    float v2 = wsum(v * v);
    float vn = fmaxf(sqrtf(v2), MINN);
    if (vn > MAXNRM) { v *= MAXNRM / vn; vn = MAXNRM; }
    float xt = artanh_(vn) / vn * v;     // logmap0
    liner[(size_t)grow * ODIM + lane] = v;
    xtf[fragaddr(grow, lane)] = f2bf(xt);
}

// ---- kernel 4: adj@xtan MFMA, 2 blocks per strip, in-block 4-wave reduce ----
__global__ __launch_bounds__(256) void gemm_agg_mfma(
    const float* __restrict__ ADJ, const unsigned short* __restrict__ xtf,
    float* __restrict__ part) {
    __shared__ float red[4][16][REDS];
    int tid = threadIdx.x, wave = tid >> 6, lane = tid & 63;
    int lrow = lane & 15, lgrp = lane >> 4;
    int rowbase = blockIdx.x * 16;       // 97 strips
    int h = blockIdx.y;
    int kc = h * 4 + wave;
    const float* arow = ADJ + (size_t)min(rowbase + lrow, NROWS - 1) * INDIM;

    f32x4 ac0 = {0,0,0,0}, ac1 = {0,0,0,0}, ac2 = {0,0,0,0}, ac3 = {0,0,0,0};
    for (int ks = kc; ks < 48; ks += 8) {
        const float* xp = arow + ks * 32 + lgrp * 8;
        float2 p0 = *(const float2*)(xp);
        float2 p1 = *(const float2*)(xp + 2);
        float2 p2 = *(const float2*)(xp + 4);
        float2 p3 = *(const float2*)(xp + 6);
        float xv[8] = {p0.x, p0.y, p1.x, p1.y, p2.x, p2.y, p3.x, p3.y};
        short8 av;
#pragma unroll
        for (int j = 0; j < 8; ++j) av[j] = (short)f2bf(xv[j]);
        const unsigned short* bp = xtf + (size_t)(ks * 4) * 512 + lane * 8;
        short8 b0 = *(const short8*)(bp);
        short8 b1 = *(const short8*)(bp + 512);
        short8 b2 = *(const short8*)(bp + 1024);
        short8 b3 = *(const short8*)(bp + 1536);
        ac0 = __builtin_amdgcn_mfma_f32_16x16x32_bf16(av, b0, ac0, 0, 0, 0);
        ac1 = __builtin_amdgcn_mfma_f32_16x16x32_bf16(av, b1, ac1, 0, 0, 0);
        ac2 = __builtin_amdgcn_mfma_f32_16x16x32_bf16(av, b2, ac2, 0, 0, 0);
        ac3 = __builtin_amdgcn_mfma_f32_16x16x32_bf16(av, b3, ac3, 0, 0, 0);
    }
    if (kc == 0) {                       // masked tail kstep 48
        short8 av;
#pragma unroll
        for (int j = 0; j < 8; ++j) {
            int k = 1536 + lgrp * 8 + j;
            av[j] = (short)f2bf((k < INDIM) ? arow[k] : 0.f);
        }
        const unsigned short* bp = xtf + (size_t)(48 * 4) * 512 + lane * 8;
        short8 b0 = *(const short8*)(bp);
        short8 b1 = *(const short8*)(bp + 512);
        short8 b2 = *(const short8*)(bp + 1024);
        short8 b3 = *(const short8*)(bp + 1536);
        ac0 = __builtin_amdgcn_mfma_f32_16x16x32_bf16(av, b0, ac0, 0, 0, 0);
        ac1 = __builtin_amdgcn_mfma_f32_16x16x32_bf16(av, b1, ac1, 0, 0, 0);
        ac2 = __builtin_amdgcn_mfma_f32_16x16x32_bf16(av, b2, ac2, 0, 0, 0);
        ac3 = __builtin_amdgcn_mfma_f32_16x16x32_bf16(av, b3, ac3, 0, 0, 0);
    }
#pragma unroll
    for (int i = 0; i < 4; ++i) {
        int r = lgrp * 4 + i;
        red[wave][r][lrow]      = ac0[i];
        red[wave][r][16 + lrow] = ac1[i];
        red[wave][r][32 + lrow] = ac2[i];
        red[wave][r][48 + lrow] = ac3[i];
    }
    __syncthreads();

#pragma unroll
    for (int j = 0; j < 4; ++j) {
        int r = wave * 4 + j;
        int grow = rowbase + r;
        if (grow < NROWS) {
            float p = red[0][r][lane] + red[1][r][lane] + red[2][r][lane] + red[3][r][lane];
            part[(size_t)(grow * 2 + h) * 64 + lane] = p;
        }
    }
}

// ---- kernel 5: reduce 2 partials + expmap0/proj + gated HypAct -> h ----
__global__ __launch_bounds__(512) void aggB(
    const float* __restrict__ part, const float* __restrict__ liner,
    const float* __restrict__ WN /*[128][64]*/, const float* __restrict__ biasnode,
    float* __restrict__ out_h) {
    __shared__ float zl[8][128];
    int wave = threadIdx.x >> 6, lane = threadIdx.x & 63;
    int grow = blockIdx.x * 8 + wave;
    if (grow >= NROWS) return;
    float s = part[(size_t)(grow * 2) * 64 + lane] + part[(size_t)(grow * 2 + 1) * 64 + lane];
    float sn2 = wsum(s * s);
    float sn = fmaxf(sqrtf(sn2), MINN);
    float th = tanhf(sn);
    float agg = th * s / sn;             // expmap0; |agg| == th
    if (th > MAXNRM) agg *= MAXNRM / th;
    float lin = liner[(size_t)grow * ODIM + lane];
    zl[wave][lane] = agg;
    zl[wave][64 + lane] = lin;           // same-wave LDS RAW, no barrier needed
    float d = biasnode[grow];
    const float* w = WN + lane;
#pragma unroll 8
    for (int f = 0; f < 128; ++f) d = fmaf(zl[wave][f], w[f * 64], d);
    d = fmaxf(d, 0.0f);
    out_h[(size_t)grow * ODIM + lane] = d * agg + (1.0f - d) * lin;
}

extern "C" void kernel_launch(void* const* d_in, const int* in_sizes, int n_in,
                              void* d_out, int out_size, void* d_ws, size_t ws_size,
                              hipStream_t stream) {
    const float* x   = (const float*)d_in[0];
    const float* adj = (const float*)d_in[1];
    const float* Wd  = (const float*)d_in[2];
    const float* Wm  = (const float*)d_in[3];
    const float* bd  = (const float*)d_in[4];
    const float* bm  = (const float*)d_in[5];
    const float* wn  = (const float*)d_in[6];
    const float* bn  = (const float*)d_in[7];
    float* out = (float*)d_out;

    const int WELEMS = ODIM * INDIM;              // 98944
    unsigned short* WfD = (unsigned short*)d_ws;  // 100352 ushorts each
    unsigned short* WfM = WfD + FRAGSZ;
    unsigned short* xtf = WfM + FRAGSZ;
    float* hbD   = (float*)(xtf + FRAGSZ);        // 3*200704 B -> 4B-aligned
    float* hbM   = hbD + 64;
    float* hb2   = hbM + 64;
    float* liner = hbD + 192;                     // 98944 floats
    float* pnorm = liner + WELEMS;                // 1546*2 = 3092 floats
    float* part  = pnorm + 3092;                  // 1546*2*64 = 197888 floats
    // total ws use ≈ 1.73 MB (< r15's proven 2.49 MB)

    int n4 = (NROWS * NROWS) / 4;                 // 597529
    prep_kernel<<<512, 256, 0, stream>>>(Wd, Wm, WfD, WfM, bd, bm, hbD, hbM, hb2,
                                         (const float4*)adj, (float4*)(out + WELEMS), n4);
    gemm_liner_mfma<<<dim3(98, 2), 256, 0, stream>>>(x, WfD, WfM, part, pnorm);
    linerB<<<194, 512, 0, stream>>>(part, pnorm, hbD, hbM, hb2, liner, xtf);
    gemm_agg_mfma<<<dim3(97, 2), 256, 0, stream>>>(adj, xtf, part);
    aggB<<<194, 512, 0, stream>>>(part, liner, wn, bn, out);
}

// Round 20
// 32.251 us; speedup vs baseline: 1.4411x; 1.0251x over previous
//
#include <hip/hip_runtime.h>
#include <math.h>

#define NROWS 1546
#define INDIM 1546
#define ODIM  64
#define NDRUG 1373
#define MINN  1e-15f
#define MAXNRM 0.996f   // (1 - 4e-3)/sqrt(c), c=1

#define KSTEPS 49                    // ceil(1546/32); step 48 is the masked tail
#define FRAGSZ (KSTEPS * 4 * 512)    // bf16 elems per packed B matrix = 100352
#define REDS   65                    // padded LDS reduce stride
#define KH     4                     // K block-split factor

typedef short  short8 __attribute__((ext_vector_type(8)));
typedef float  f32x4  __attribute__((ext_vector_type(4)));

__device__ __forceinline__ unsigned short f2bf(float f) {   // RNE f32->bf16
    unsigned u = __float_as_uint(f);
    u += 0x7FFFu + ((u >> 16) & 1u);
    return (unsigned short)(u >> 16);
}

__device__ __forceinline__ int fragaddr(int k, int col) {   // B-frag element addr
    return ((k >> 5) * 4 + (col >> 4)) * 512 + (((k & 31) >> 3) * 16 + (col & 15)) * 8 + (k & 7);
}

__device__ __forceinline__ float artanh_(float x) {
    x = fminf(fmaxf(x, -1.0f + 1e-7f), 1.0f - 1e-7f);
    return 0.5f * (log1pf(x) - log1pf(-x));
}

__device__ __forceinline__ float wsum(float v) {
#pragma unroll
    for (int off = 32; off > 0; off >>= 1) v += __shfl_xor(v, off, 64);
    return v;
}

// ---- kernel 1: W -> bf16 B-frags (blocks 0-63), bias (64), adj copy (65+) ----
__global__ void prep_kernel(const float* __restrict__ Wd, const float* __restrict__ Wm,
                            unsigned short* __restrict__ WfD, unsigned short* __restrict__ WfM,
                            const float* __restrict__ bd, const float* __restrict__ bm,
                            float* __restrict__ hbD, float* __restrict__ hbM,
                            float* __restrict__ hb2,
                            const float4* __restrict__ adj4, float4* __restrict__ adjout4,
                            int n4) {
    int tid = threadIdx.x;
    if (blockIdx.x < 64) {
        int total = 64 * 1568;     // 100352 per matrix
        for (int i = blockIdx.x * 256 + tid; i < total; i += 64 * 256) {
            int o = i / 1568, k = i - o * 1568;
            int addr = fragaddr(k, o);
            float vd = (k < INDIM) ? Wd[o * INDIM + k] : 0.f;
            float vm = (k < INDIM) ? Wm[o * INDIM + k] : 0.f;
            WfD[addr] = f2bf(vd);
            WfM[addr] = f2bf(vm);
        }
        return;
    }
    if (blockIdx.x == 64) {
        if (tid < 128) {
            int wave = tid >> 6, lane = tid & 63;
            const float* b = wave ? bm : bd;
            float v = b[lane];
            float un2 = wsum(v * v);
            float un = fmaxf(sqrtf(un2), MINN);
            float e = tanhf(un) * v / un;
            float en2 = wsum(e * e);
            float en = fmaxf(sqrtf(en2), MINN);
            float scl = (en > MAXNRM) ? (MAXNRM / en) : 1.0f;
            float* hb = wave ? hbM : hbD;
            hb[lane] = e * scl;
            if (lane == 0) hb2[wave] = en2 * scl * scl;
        }
        return;
    }
    int nb = gridDim.x - 65;
    for (int i = (blockIdx.x - 65) * 256 + tid; i < n4; i += nb * 256)
        adjout4[i] = adj4[i];
}

// ---- kernel 2: x@W^T MFMA, KH blocks per strip (K quarters), in-block reduce ----
__global__ __launch_bounds__(256) void gemm_liner_mfma(
    const float* __restrict__ X,
    const unsigned short* __restrict__ WfD, const unsigned short* __restrict__ WfM,
    float* __restrict__ part, float* __restrict__ pnorm) {
    __shared__ float red[4][16][REDS];   // 16.6 KB
    __shared__ float ssl[4][16];
    int tid = threadIdx.x, wave = tid >> 6, lane = tid & 63;
    int lrow = lane & 15, lgrp = lane >> 4;
    int s = blockIdx.x;                  // 0..97; 97 = strip 85 redo with Wm
    int h = blockIdx.y;                  // K quarter
    int kc = h * 4 + wave;               // 0..15
    int strip = (s == 97) ? 85 : s;
    int rowbase = strip * 16;
    const unsigned short* Bf = (s <= 85) ? WfD : WfM;
    int lo = (s == 97) ? NDRUG : 0;
    int hi = (s == 85) ? NDRUG : NROWS;
    const float* arow = X + (size_t)min(rowbase + lrow, NROWS - 1) * INDIM;

    f32x4 ac0 = {0,0,0,0}, ac1 = {0,0,0,0}, ac2 = {0,0,0,0}, ac3 = {0,0,0,0};
    float ss = 0.f;
#pragma unroll
    for (int ii = 0; ii < 3; ++ii) {     // ksteps kc, kc+16, kc+32
        int ks = kc + 16 * ii;
        const float* xp = arow + ks * 32 + lgrp * 8;
        float2 p0 = *(const float2*)(xp);
        float2 p1 = *(const float2*)(xp + 2);
        float2 p2 = *(const float2*)(xp + 4);
        float2 p3 = *(const float2*)(xp + 6);
        float xv[8] = {p0.x, p0.y, p1.x, p1.y, p2.x, p2.y, p3.x, p3.y};
        short8 av;
#pragma unroll
        for (int j = 0; j < 8; ++j) { ss = fmaf(xv[j], xv[j], ss); av[j] = (short)f2bf(xv[j]); }
        const unsigned short* bp = Bf + (size_t)(ks * 4) * 512 + lane * 8;
        short8 b0 = *(const short8*)(bp);
        short8 b1 = *(const short8*)(bp + 512);
        short8 b2 = *(const short8*)(bp + 1024);
        short8 b3 = *(const short8*)(bp + 1536);
        ac0 = __builtin_amdgcn_mfma_f32_16x16x32_bf16(av, b0, ac0, 0, 0, 0);
        ac1 = __builtin_amdgcn_mfma_f32_16x16x32_bf16(av, b1, ac1, 0, 0, 0);
        ac2 = __builtin_amdgcn_mfma_f32_16x16x32_bf16(av, b2, ac2, 0, 0, 0);
        ac3 = __builtin_amdgcn_mfma_f32_16x16x32_bf16(av, b3, ac3, 0, 0, 0);
    }
    if (kc == 0) {                       // masked tail kstep 48 (k = 1536..1567)
        short8 av;
#pragma unroll
        for (int j = 0; j < 8; ++j) {
            int k = 1536 + lgrp * 8 + j;
            float v = (k < INDIM) ? arow[k] : 0.f;
            ss = fmaf(v, v, ss);
            av[j] = (short)f2bf(v);
        }
        const unsigned short* bp = Bf + (size_t)(48 * 4) * 512 + lane * 8;
        short8 b0 = *(const short8*)(bp);
        short8 b1 = *(const short8*)(bp + 512);
        short8 b2 = *(const short8*)(bp + 1024);
        short8 b3 = *(const short8*)(bp + 1536);
        ac0 = __builtin_amdgcn_mfma_f32_16x16x32_bf16(av, b0, ac0, 0, 0, 0);
        ac1 = __builtin_amdgcn_mfma_f32_16x16x32_bf16(av, b1, ac1, 0, 0, 0);
        ac2 = __builtin_amdgcn_mfma_f32_16x16x32_bf16(av, b2, ac2, 0, 0, 0);
        ac3 = __builtin_amdgcn_mfma_f32_16x16x32_bf16(av, b3, ac3, 0, 0, 0);
    }
    ss += __shfl_xor(ss, 16, 64);        // sum 4 lane-groups sharing a row
    ss += __shfl_xor(ss, 32, 64);
    if (lane < 16) ssl[wave][lrow] = ss;
#pragma unroll
    for (int i = 0; i < 4; ++i) {        // C/D layout: row=lgrp*4+i, col=t*16+lrow
        int r = lgrp * 4 + i;
        red[wave][r][lrow]      = ac0[i];
        red[wave][r][16 + lrow] = ac1[i];
        red[wave][r][32 + lrow] = ac2[i];
        red[wave][r][48 + lrow] = ac3[i];
    }
    __syncthreads();

#pragma unroll
    for (int j = 0; j < 4; ++j) {        // wave handles 4 rows
        int r = wave * 4 + j;
        int grow = rowbase + r;
        if (grow >= lo && grow < hi) {
            float p = red[0][r][lane] + red[1][r][lane] + red[2][r][lane] + red[3][r][lane];
            part[(size_t)(grow * KH + h) * 64 + lane] = p;
        }
        if (s != 97 && grow < NROWS && lane == 0) {   // row norms: W-independent
            pnorm[grow * KH + h] = ssl[0][r] + ssl[1][r] + ssl[2][r] + ssl[3][r];
        }
    }
}

// ---- kernel 3: reduce KH partials + hyperbolic epilogue -> liner, xtf ----
__global__ __launch_bounds__(512) void linerB(
    const float* __restrict__ part, const float* __restrict__ pnorm,
    const float* __restrict__ hbD, const float* __restrict__ hbM, const float* __restrict__ hb2v,
    float* __restrict__ liner, unsigned short* __restrict__ xtf) {
    int wave = threadIdx.x >> 6, lane = threadIdx.x & 63;
    int grow = blockIdx.x * 8 + wave;
    if (grow >= NROWS) {                 // block 193 waves 2-7: zero-pad rows 1546..1567
        for (int row = grow; row < 1568; row += 6)
            xtf[fragaddr(row, lane)] = 0;
        return;
    }
    float mx = 0.f, xn2 = 0.f;
#pragma unroll
    for (int h = 0; h < KH; ++h) {
        mx += part[(size_t)(grow * KH + h) * 64 + lane];
        xn2 += pnorm[grow * KH + h];
    }

    float mxn2 = wsum(mx * mx);
    float xn = fmaxf(sqrtf(xn2), MINN);
    float mxn = fmaxf(sqrtf(mxn2), MINN);
    float g = mxn / xn * artanh_(xn);
    float t = tanhf(g);
    float res = t * mx / mxn;            // |res| == |t|
    float rn = fabsf(t);
    if (rn > MAXNRM) { res *= MAXNRM / rn; rn = MAXNRM; }
    const float* hb = (grow < NDRUG) ? hbD : hbM;
    float y = hb[lane];
    float y2 = hb2v[(grow < NDRUG) ? 0 : 1];
    float x2 = rn * rn;
    float xy = wsum(res * y);
    float num = (1.0f + 2.0f * xy + y2) * res + (1.0f - x2) * y;
    float den = 1.0f + 2.0f * xy + x2 * y2;
    float v = num / fmaxf(den, MINN);
    float v2 = wsum(v * v);
    float vn = fmaxf(sqrtf(v2), MINN);
    if (vn > MAXNRM) { v *= MAXNRM / vn; vn = MAXNRM; }
    float xt = artanh_(vn) / vn * v;     // logmap0
    liner[(size_t)grow * ODIM + lane] = v;
    xtf[fragaddr(grow, lane)] = f2bf(xt);
}

// ---- kernel 4: adj@xtan MFMA, KH blocks per strip, in-block reduce ----
__global__ __launch_bounds__(256) void gemm_agg_mfma(
    const float* __restrict__ ADJ, const unsigned short* __restrict__ xtf,
    float* __restrict__ part) {
    __shared__ float red[4][16][REDS];
    int tid = threadIdx.x, wave = tid >> 6, lane = tid & 63;
    int lrow = lane & 15, lgrp = lane >> 4;
    int rowbase = blockIdx.x * 16;       // 97 strips
    int h = blockIdx.y;
    int kc = h * 4 + wave;               // 0..15
    const float* arow = ADJ + (size_t)min(rowbase + lrow, NROWS - 1) * INDIM;

    f32x4 ac0 = {0,0,0,0}, ac1 = {0,0,0,0}, ac2 = {0,0,0,0}, ac3 = {0,0,0,0};
#pragma unroll
    for (int ii = 0; ii < 3; ++ii) {
        int ks = kc + 16 * ii;
        const float* xp = arow + ks * 32 + lgrp * 8;
        float2 p0 = *(const float2*)(xp);
        float2 p1 = *(const float2*)(xp + 2);
        float2 p2 = *(const float2*)(xp + 4);
        float2 p3 = *(const float2*)(xp + 6);
        float xv[8] = {p0.x, p0.y, p1.x, p1.y, p2.x, p2.y, p3.x, p3.y};
        short8 av;
#pragma unroll
        for (int j = 0; j < 8; ++j) av[j] = (short)f2bf(xv[j]);
        const unsigned short* bp = xtf + (size_t)(ks * 4) * 512 + lane * 8;
        short8 b0 = *(const short8*)(bp);
        short8 b1 = *(const short8*)(bp + 512);
        short8 b2 = *(const short8*)(bp + 1024);
        short8 b3 = *(const short8*)(bp + 1536);
        ac0 = __builtin_amdgcn_mfma_f32_16x16x32_bf16(av, b0, ac0, 0, 0, 0);
        ac1 = __builtin_amdgcn_mfma_f32_16x16x32_bf16(av, b1, ac1, 0, 0, 0);
        ac2 = __builtin_amdgcn_mfma_f32_16x16x32_bf16(av, b2, ac2, 0, 0, 0);
        ac3 = __builtin_amdgcn_mfma_f32_16x16x32_bf16(av, b3, ac3, 0, 0, 0);
    }
    if (kc == 0) {                       // masked tail kstep 48
        short8 av;
#pragma unroll
        for (int j = 0; j < 8; ++j) {
            int k = 1536 + lgrp * 8 + j;
            av[j] = (short)f2bf((k < INDIM) ? arow[k] : 0.f);
        }
        const unsigned short* bp = xtf + (size_t)(48 * 4) * 512 + lane * 8;
        short8 b0 = *(const short8*)(bp);
        short8 b1 = *(const short8*)(bp + 512);
        short8 b2 = *(const short8*)(bp + 1024);
        short8 b3 = *(const short8*)(bp + 1536);
        ac0 = __builtin_amdgcn_mfma_f32_16x16x32_bf16(av, b0, ac0, 0, 0, 0);
        ac1 = __builtin_amdgcn_mfma_f32_16x16x32_bf16(av, b1, ac1, 0, 0, 0);
        ac2 = __builtin_amdgcn_mfma_f32_16x16x32_bf16(av, b2, ac2, 0, 0, 0);
        ac3 = __builtin_amdgcn_mfma_f32_16x16x32_bf16(av, b3, ac3, 0, 0, 0);
    }
#pragma unroll
    for (int i = 0; i < 4; ++i) {
        int r = lgrp * 4 + i;
        red[wave][r][lrow]      = ac0[i];
        red[wave][r][16 + lrow] = ac1[i];
        red[wave][r][32 + lrow] = ac2[i];
        red[wave][r][48 + lrow] = ac3[i];
    }
    __syncthreads();

#pragma unroll
    for (int j = 0; j < 4; ++j) {
        int r = wave * 4 + j;
        int grow = rowbase + r;
        if (grow < NROWS) {
            float p = red[0][r][lane] + red[1][r][lane] + red[2][r][lane] + red[3][r][lane];
            part[(size_t)(grow * KH + h) * 64 + lane] = p;
        }
    }
}

// ---- kernel 5: reduce KH partials + expmap0/proj + gated HypAct -> h ----
__global__ __launch_bounds__(512) void aggB(
    const float* __restrict__ part, const float* __restrict__ liner,
    const float* __restrict__ WN /*[128][64]*/, const float* __restrict__ biasnode,
    float* __restrict__ out_h) {
    __shared__ float zl[8][128];
    int wave = threadIdx.x >> 6, lane = threadIdx.x & 63;
    int grow = blockIdx.x * 8 + wave;
    if (grow >= NROWS) return;
    float s = 0.f;
#pragma unroll
    for (int h = 0; h < KH; ++h) s += part[(size_t)(grow * KH + h) * 64 + lane];
    float sn2 = wsum(s * s);
    float sn = fmaxf(sqrtf(sn2), MINN);
    float th = tanhf(sn);
    float agg = th * s / sn;             // expmap0; |agg| == th
    if (th > MAXNRM) agg *= MAXNRM / th;
    float lin = liner[(size_t)grow * ODIM + lane];
    zl[wave][lane] = agg;
    zl[wave][64 + lane] = lin;           // same-wave LDS RAW, no barrier needed
    float d = biasnode[grow];
    const float* w = WN + lane;
#pragma unroll 8
    for (int f = 0; f < 128; ++f) d = fmaf(zl[wave][f], w[f * 64], d);
    d = fmaxf(d, 0.0f);
    out_h[(size_t)grow * ODIM + lane] = d * agg + (1.0f - d) * lin;
}

extern "C" void kernel_launch(void* const* d_in, const int* in_sizes, int n_in,
                              void* d_out, int out_size, void* d_ws, size_t ws_size,
                              hipStream_t stream) {
    const float* x   = (const float*)d_in[0];
    const float* adj = (const float*)d_in[1];
    const float* Wd  = (const float*)d_in[2];
    const float* Wm  = (const float*)d_in[3];
    const float* bd  = (const float*)d_in[4];
    const float* bm  = (const float*)d_in[5];
    const float* wn  = (const float*)d_in[6];
    const float* bn  = (const float*)d_in[7];
    float* out = (float*)d_out;

    const int WELEMS = ODIM * INDIM;              // 98944
    unsigned short* WfD = (unsigned short*)d_ws;  // 100352 ushorts each
    unsigned short* WfM = WfD + FRAGSZ;
    unsigned short* xtf = WfM + FRAGSZ;
    float* hbD   = (float*)(xtf + FRAGSZ);        // 3*200704 B -> 4B-aligned
    float* hbM   = hbD + 64;
    float* hb2   = hbM + 64;
    float* liner = hbD + 192;                     // 98944 floats
    float* pnorm = liner + WELEMS;                // 1546*4 = 6184 floats
    float* part  = pnorm + 6184;                  // 1546*4*64 = 395776 floats
    // total ws use ≈ 2.6 MB (r15 proved 2.59 MB fits)

    int n4 = (NROWS * NROWS) / 4;                 // 597529
    prep_kernel<<<512, 256, 0, stream>>>(Wd, Wm, WfD, WfM, bd, bm, hbD, hbM, hb2,
                                         (const float4*)adj, (float4*)(out + WELEMS), n4);
    gemm_liner_mfma<<<dim3(98, KH), 256, 0, stream>>>(x, WfD, WfM, part, pnorm);
    linerB<<<194, 512, 0, stream>>>(part, pnorm, hbD, hbM, hb2, liner, xtf);
    gemm_agg_mfma<<<dim3(97, KH), 256, 0, stream>>>(adj, xtf, part);
    aggB<<<194, 512, 0, stream>>>(part, liner, wn, bn, out);
}